// Round 3
// baseline (770.210 us; speedup 1.0000x reference)
//
#include <hip/hip_runtime.h>
#include <hip/hip_bf16.h>
#include <math.h>

#define UCNT 50000
#define ICNT 25000
#define NNODE 75000
#define DDIM 64
#define BB 4096
#define EPS_C 0.2f
#define INV_TEMP 5.0f
#define NB_SCAN ((NNODE + 255) / 256)   // 293

__device__ __forceinline__ float wave_sum(float x) {
#pragma unroll
  for (int m = 32; m >= 1; m >>= 1) x += __shfl_xor(x, m, 64);
  return x;
}

// ---------------- init: zero counts, rowsums, accumulators ----------------
__global__ void init_kernel(int* __restrict__ counts, float* __restrict__ rowsum_u,
                            float* __restrict__ rowsum_i, float* __restrict__ accum) {
  int i = blockIdx.x * blockDim.x + threadIdx.x;
  if (i < NNODE) counts[i] = 0;
  if (i < BB) { rowsum_u[i] = 0.f; rowsum_i[i] = 0.f; }
  if (i < 2) accum[i] = 0.f;
}

// ---------------- histogram ----------------
__global__ void hist_kernel(const int* __restrict__ src, int* __restrict__ counts, int ne) {
  int i = blockIdx.x * blockDim.x + threadIdx.x;
  int stride = gridDim.x * blockDim.x;
  for (; i < ne; i += stride) atomicAdd(&counts[src[i]], 1);
}

// ---------------- hierarchical scan: pass 1 — per-block sums ----------------
__global__ __launch_bounds__(256) void blocksum_kernel(const int* __restrict__ counts,
                                                       int* __restrict__ bsum, int n) {
  int t = threadIdx.x;
  int i = blockIdx.x * 256 + t;
  int c = (i < n) ? counts[i] : 0;
#pragma unroll
  for (int m = 32; m >= 1; m >>= 1) c += __shfl_xor(c, m, 64);
  __shared__ int ws[4];
  if ((t & 63) == 0) ws[t >> 6] = c;
  __syncthreads();
  if (t == 0) bsum[blockIdx.x] = ws[0] + ws[1] + ws[2] + ws[3];
}

// ---------------- hierarchical scan: pass 2 — scan the 293 block sums ----------------
__global__ __launch_bounds__(512) void bscan_kernel(const int* __restrict__ bsum,
                                                    int* __restrict__ boff, int nb) {
  int t = threadIdx.x;
  int lane = t & 63, wid = t >> 6;
  int c = (t < nb) ? bsum[t] : 0;
  int v = c;
#pragma unroll
  for (int d = 1; d < 64; d <<= 1) {
    int u = __shfl_up(v, d, 64);
    if (lane >= d) v += u;
  }
  __shared__ int ws[8], wo[8];
  if (lane == 63) ws[wid] = v;
  __syncthreads();
  if (t == 0) {
    int run = 0;
    for (int k = 0; k < 8; ++k) { wo[k] = run; run += ws[k]; }
  }
  __syncthreads();
  if (t < nb) boff[t] = v - c + wo[wid];
}

// ---------------- hierarchical scan: pass 3 — local scan + offset ----------------
__global__ __launch_bounds__(256) void scanout_kernel(const int* __restrict__ counts,
                                                      const int* __restrict__ boff,
                                                      int* __restrict__ row_ptr,
                                                      int* __restrict__ cursor, int n) {
  int t = threadIdx.x;
  int lane = t & 63, wid = t >> 6;
  int i = blockIdx.x * 256 + t;
  int c = (i < n) ? counts[i] : 0;
  int v = c;
#pragma unroll
  for (int d = 1; d < 64; d <<= 1) {
    int u = __shfl_up(v, d, 64);
    if (lane >= d) v += u;
  }
  __shared__ int ws[4], wo[4];
  if (lane == 63) ws[wid] = v;
  __syncthreads();
  if (t == 0) {
    int run = 0;
    for (int k = 0; k < 4; ++k) { wo[k] = run; run += ws[k]; }
  }
  __syncthreads();
  int excl = v - c + wo[wid] + boff[blockIdx.x];
  if (i < n) {
    row_ptr[i] = excl;
    cursor[i] = excl;
    if (i == n - 1) row_ptr[n] = excl + c;
  }
}

// ---------------- scatter into CSR (dst only — no values!) ----------------
__global__ void scatter_kernel(const int* __restrict__ src, const int* __restrict__ dst,
                               int* __restrict__ cursor, int* __restrict__ csr_dst, int ne) {
  int i = blockIdx.x * blockDim.x + threadIdx.x;
  int stride = gridDim.x * blockDim.x;
  for (; i < ne; i += stride) {
    int slot = atomicAdd(&cursor[src[i]], 1);
    csr_dst[slot] = dst[i];
  }
}

// ---------------- prescale: y_init[n] = table[n] * rsqrt(max(deg,1)) ----------------
__global__ __launch_bounds__(256) void prescale_kernel(const float* __restrict__ ut,
                                                       const float* __restrict__ it,
                                                       const int* __restrict__ counts,
                                                       float* __restrict__ y) {
  int idx = blockIdx.x * 256 + threadIdx.x;   // one float4 per thread
  if (idx >= NNODE * 16) return;
  int n = idx >> 4;
  float sc = rsqrtf(fmaxf((float)counts[n], 1.f));
  const float* srcp = (n < UCNT) ? (ut + (size_t)n * DDIM)
                                 : (it + (size_t)(n - UCNT) * DDIM);
  float4 v = *(const float4*)(srcp + (idx & 15) * 4);
  v.x *= sc; v.y *= sc; v.z *= sc; v.w *= sc;
  *(float4*)((float*)y + (size_t)idx * 4) = v;
}

// ---------------- SpMM (plain gather-sum of prescaled rows) + noise ----------------
// writes y_out[r] = x_out[r] * rsqrt(max(deg_r,1))  (pre-scaled for next layer;
// batch_kernel recovers x by multiplying with sqrt(max(deg,1)))
__global__ __launch_bounds__(256) void spmm_kernel(const float* __restrict__ y_in,
                                                   const int* __restrict__ row_ptr,
                                                   const int* __restrict__ csr_dst,
                                                   const int* __restrict__ counts,
                                                   const float* __restrict__ noise,
                                                   float* __restrict__ y_out) {
  int wave = blockIdx.x * 4 + (threadIdx.x >> 6);
  int lane = threadIdx.x & 63;
  if (wave >= NNODE) return;
  int r = wave;
  int beg = row_ptr[r], endp = row_ptr[r + 1];
  int g = lane >> 4, l16 = lane & 15;
  float4 acc = {0.f, 0.f, 0.f, 0.f};
  for (int e0 = beg; e0 < endp; e0 += 64) {
    int e = e0 + lane;
    int d = (e < endp) ? csr_dst[e] : 0;
    int cnt = min(64, endp - e0);
    for (int j = 0; j < cnt; j += 4) {
      int dj = __shfl(d, j + g, 64);
      if (j + g < cnt) {    // group-uniform branch
        float4 xv = *(const float4*)(y_in + (size_t)dj * DDIM + l16 * 4);
        acc.x += xv.x; acc.y += xv.y; acc.z += xv.z; acc.w += xv.w;
      }
    }
  }
  // reduce the 4 edge-groups
#pragma unroll
  for (int m = 16; m <= 32; m <<= 1) {
    acc.x += __shfl_xor(acc.x, m, 64);
    acc.y += __shfl_xor(acc.y, m, 64);
    acc.z += __shfl_xor(acc.z, m, 64);
    acc.w += __shfl_xor(acc.w, m, 64);
  }
  float sc = rsqrtf(fmaxf((float)counts[r], 1.f));
  acc.x *= sc; acc.y *= sc; acc.z *= sc; acc.w *= sc;   // x (pre-noise)
  float4 nf = *(const float4*)(noise + (size_t)r * DDIM + l16 * 4);
  float ss = nf.x * nf.x + nf.y * nf.y + nf.z * nf.z + nf.w * nf.w;
#pragma unroll
  for (int m = 1; m <= 8; m <<= 1) ss += __shfl_xor(ss, m, 64);  // 16-lane group = row
  float inv = EPS_C / fmaxf(sqrtf(ss), 1e-12f);
  float4 o;
  o.x = acc.x + ((acc.x > 0.f) ? 1.f : ((acc.x < 0.f) ? -1.f : 0.f)) * nf.x * inv;
  o.y = acc.y + ((acc.y > 0.f) ? 1.f : ((acc.y < 0.f) ? -1.f : 0.f)) * nf.y * inv;
  o.z = acc.z + ((acc.z > 0.f) ? 1.f : ((acc.z < 0.f) ? -1.f : 0.f)) * nf.z * inv;
  o.w = acc.w + ((acc.w > 0.f) ? 1.f : ((acc.w < 0.f) ? -1.f : 0.f)) * nf.w * inv;
  o.x *= sc; o.y *= sc; o.z *= sc; o.w *= sc;           // store y = x * sc
  if (g == 0) *(float4*)(y_out + (size_t)r * DDIM + l16 * 4) = o;
}

// ---------------- batch gather: BPR, reg, normalized InfoNCE inputs ----------------
// yb* hold x * rsqrt(max(deg,1)); recover x by * sqrt(max(deg,1)).
__global__ __launch_bounds__(256) void batch_kernel(
    const float* __restrict__ yb0, const float* __restrict__ yb1, const float* __restrict__ yb2,
    const float* __restrict__ ut, const float* __restrict__ it,
    const int* __restrict__ counts,
    const int* __restrict__ user, const int* __restrict__ pos, const int* __restrict__ neg,
    float* __restrict__ z1u, float* __restrict__ z2u,
    float* __restrict__ z1i, float* __restrict__ z2i,
    float* __restrict__ pos_u, float* __restrict__ pos_i, float* __restrict__ accum) {
  int wave = blockIdx.x * (blockDim.x >> 6) + (threadIdx.x >> 6);
  int lane = threadIdx.x & 63;
  if (wave >= BB) return;
  int b = wave;
  int iu = user[b], ip = pos[b], ing = neg[b];
  float s_u = sqrtf(fmaxf((float)counts[iu], 1.f));
  float s_p = sqrtf(fmaxf((float)counts[UCNT + ip], 1.f));
  float s_n = sqrtf(fmaxf((float)counts[UCNT + ing], 1.f));
  size_t ru = (size_t)iu * DDIM + lane;
  size_t rp = (size_t)(UCNT + ip) * DDIM + lane;
  size_t rn = (size_t)(UCNT + ing) * DDIM + lane;
  float cu = yb0[ru] * s_u;        // x_cl user row
  float ci = yb0[rp] * s_p;        // x_cl positive-item row
  float ue = (cu + (yb1[ru] + yb2[ru]) * s_u) * (1.f / 3.f);
  float pe = (ci + (yb1[rp] + yb2[rp]) * s_p) * (1.f / 3.f);
  float ne = (yb0[rn] + yb1[rn] + yb2[rn]) * s_n * (1.f / 3.f);

  float ps = wave_sum(ue * pe);
  float ns = wave_sum(ue * ne);
  float x = ns - ps;
  float sp = fmaxf(x, 0.f) + log1pf(expf(-fabsf(x)));

  float eu = ut[(size_t)iu * DDIM + lane];
  float ep = it[(size_t)ip * DDIM + lane];
  float en = it[(size_t)ing * DDIM + lane];
  float rr = wave_sum(eu * eu + ep * ep + en * en);
  if (lane == 0) { atomicAdd(&accum[0], sp); atomicAdd(&accum[1], rr); }

  float n1 = fmaxf(sqrtf(wave_sum(cu * cu)), 1e-12f);
  float n2 = fmaxf(sqrtf(wave_sum(ue * ue)), 1e-12f);
  float d12 = wave_sum(cu * ue);
  z1u[(size_t)b * DDIM + lane] = cu / n1;
  z2u[(size_t)b * DDIM + lane] = ue / n2;
  if (lane == 0) pos_u[b] = d12 / (n1 * n2) * INV_TEMP;

  float m1 = fmaxf(sqrtf(wave_sum(ci * ci)), 1e-12f);
  float m2 = fmaxf(sqrtf(wave_sum(pe * pe)), 1e-12f);
  float e12 = wave_sum(ci * pe);
  z1i[(size_t)b * DDIM + lane] = ci / m1;
  z2i[(size_t)b * DDIM + lane] = pe / m2;
  if (lane == 0) pos_i[b] = e12 / (m1 * m2) * INV_TEMP;
}

// ---------------- InfoNCE similarity tile ----------------
__global__ __launch_bounds__(256) void infonce_kernel(const float* __restrict__ Z1,
                                                      const float* __restrict__ Z2,
                                                      float* __restrict__ rowsum) {
  __shared__ float S1[64][65];
  __shared__ float S2[64][65];
  __shared__ float red[64][17];
  int t = threadIdx.x;
  int i0 = blockIdx.y * 64, j0 = blockIdx.x * 64;
#pragma unroll
  for (int rep = 0; rep < 4; ++rep) {
    int vlin = rep * 256 + t;       // float4 index in 64x16
    int row = vlin >> 4;
    int c4 = (vlin & 15) * 4;
    float4 a = *(const float4*)(Z1 + (size_t)(i0 + row) * DDIM + c4);
    S1[c4 + 0][row] = a.x; S1[c4 + 1][row] = a.y; S1[c4 + 2][row] = a.z; S1[c4 + 3][row] = a.w;
    float4 b = *(const float4*)(Z2 + (size_t)(j0 + row) * DDIM + c4);
    S2[c4 + 0][row] = b.x; S2[c4 + 1][row] = b.y; S2[c4 + 2][row] = b.z; S2[c4 + 3][row] = b.w;
  }
  __syncthreads();
  int ti = (t & 15) * 4;
  int tj = (t >> 4) * 4;
  float acc[4][4] = {};
  for (int k = 0; k < 64; ++k) {
    float4 av = *(const float4*)&S1[k][ti];
    float4 bv = *(const float4*)&S2[k][tj];
    float a[4] = {av.x, av.y, av.z, av.w};
    float b[4] = {bv.x, bv.y, bv.z, bv.w};
#pragma unroll
    for (int r = 0; r < 4; ++r)
#pragma unroll
      for (int c = 0; c < 4; ++c) acc[r][c] += a[r] * b[c];
  }
  int q = t >> 4;
#pragma unroll
  for (int r = 0; r < 4; ++r) {
    float s = __expf(acc[r][0] * INV_TEMP) + __expf(acc[r][1] * INV_TEMP) +
              __expf(acc[r][2] * INV_TEMP) + __expf(acc[r][3] * INV_TEMP);
    red[ti + r][q] = s;
  }
  __syncthreads();
  if (t < 64) {
    float tot = 0.f;
#pragma unroll
    for (int q2 = 0; q2 < 16; ++q2) tot += red[t][q2];
    atomicAdd(&rowsum[i0 + t], tot);
  }
}

// ---------------- finalize ----------------
__global__ __launch_bounds__(256) void finalize_kernel(const float* __restrict__ rowsum_u,
                                                       const float* __restrict__ pos_u,
                                                       const float* __restrict__ rowsum_i,
                                                       const float* __restrict__ pos_i,
                                                       const float* __restrict__ accum,
                                                       float* __restrict__ out) {
  int t = threadIdx.x;
  float su = 0.f, si = 0.f;
  for (int i = t; i < BB; i += 256) {
    su += logf(rowsum_u[i]) - pos_u[i];
    si += logf(rowsum_i[i]) - pos_i[i];
  }
  su = wave_sum(su);
  si = wave_sum(si);
  __shared__ float sh[8];
  int lane = t & 63, wid = t >> 6;
  if (lane == 0) { sh[wid] = su; sh[4 + wid] = si; }
  __syncthreads();
  if (t == 0) {
    float SU = sh[0] + sh[1] + sh[2] + sh[3];
    float SI = sh[4] + sh[5] + sh[6] + sh[7];
    out[0] = accum[0] * (1.f / BB);
    out[1] = 1e-4f * 0.5f * accum[1] * (1.f / BB);
    out[2] = 0.2f * ((SU + SI) * (1.f / BB));
  }
}

extern "C" void kernel_launch(void* const* d_in, const int* in_sizes, int n_in,
                              void* d_out, int out_size, void* d_ws, size_t ws_size,
                              hipStream_t stream) {
  const float* user_table = (const float*)d_in[0];
  const float* item_table = (const float*)d_in[1];
  const float* noise      = (const float*)d_in[3];
  const int*   edge_src   = (const int*)d_in[4];
  const int*   edge_dst   = (const int*)d_in[5];
  const int*   user       = (const int*)d_in[6];
  const int*   positive   = (const int*)d_in[7];
  const int*   negative   = (const int*)d_in[8];
  const int E2 = in_sizes[2];  // 2,000,000

  char* w = (char*)d_ws;
  auto alloc = [&](size_t bytes) -> void* {
    void* p = (void*)w;
    w += (bytes + 255) & ~(size_t)255;
    return p;
  };
  int*   counts   = (int*)alloc((size_t)NNODE * 4);
  int*   row_ptr  = (int*)alloc((size_t)(NNODE + 1) * 4);
  int*   cursor   = (int*)alloc((size_t)NNODE * 4);
  int*   bsum     = (int*)alloc((size_t)NB_SCAN * 4);
  int*   boff     = (int*)alloc((size_t)NB_SCAN * 4);
  int*   csr_dst  = (int*)alloc((size_t)E2 * 4);
  float* y_init   = (float*)alloc((size_t)NNODE * DDIM * 4);
  float* yb0      = (float*)alloc((size_t)NNODE * DDIM * 4);
  float* yb1      = (float*)alloc((size_t)NNODE * DDIM * 4);
  float* yb2      = (float*)alloc((size_t)NNODE * DDIM * 4);
  float* z1u      = (float*)alloc((size_t)BB * DDIM * 4);
  float* z2u      = (float*)alloc((size_t)BB * DDIM * 4);
  float* z1i      = (float*)alloc((size_t)BB * DDIM * 4);
  float* z2i      = (float*)alloc((size_t)BB * DDIM * 4);
  float* pos_u    = (float*)alloc((size_t)BB * 4);
  float* pos_i    = (float*)alloc((size_t)BB * 4);
  float* rowsum_u = (float*)alloc((size_t)BB * 4);
  float* rowsum_i = (float*)alloc((size_t)BB * 4);
  float* accum    = (float*)alloc(256);

  init_kernel<<<(NNODE + 255) / 256, 256, 0, stream>>>(counts, rowsum_u, rowsum_i, accum);
  hist_kernel<<<2048, 256, 0, stream>>>(edge_src, counts, E2);
  blocksum_kernel<<<NB_SCAN, 256, 0, stream>>>(counts, bsum, NNODE);
  bscan_kernel<<<1, 512, 0, stream>>>(bsum, boff, NB_SCAN);
  scanout_kernel<<<NB_SCAN, 256, 0, stream>>>(counts, boff, row_ptr, cursor, NNODE);
  scatter_kernel<<<2048, 256, 0, stream>>>(edge_src, edge_dst, cursor, csr_dst, E2);
  prescale_kernel<<<(NNODE * 16 + 255) / 256, 256, 0, stream>>>(user_table, item_table,
                                                                counts, y_init);
  const int spmm_blocks = (NNODE + 3) / 4;  // 4 waves per 256-thread block
  spmm_kernel<<<spmm_blocks, 256, 0, stream>>>(y_init, row_ptr, csr_dst, counts,
                                               noise + (size_t)0 * NNODE * DDIM, yb0);
  spmm_kernel<<<spmm_blocks, 256, 0, stream>>>(yb0, row_ptr, csr_dst, counts,
                                               noise + (size_t)1 * NNODE * DDIM, yb1);
  spmm_kernel<<<spmm_blocks, 256, 0, stream>>>(yb1, row_ptr, csr_dst, counts,
                                               noise + (size_t)2 * NNODE * DDIM, yb2);
  batch_kernel<<<BB / 4, 256, 0, stream>>>(yb0, yb1, yb2, user_table, item_table, counts,
                                           user, positive, negative,
                                           z1u, z2u, z1i, z2i, pos_u, pos_i, accum);
  dim3 ig(BB / 64, BB / 64);
  infonce_kernel<<<ig, 256, 0, stream>>>(z1u, z2u, rowsum_u);
  infonce_kernel<<<ig, 256, 0, stream>>>(z1i, z2i, rowsum_i);
  finalize_kernel<<<1, 256, 0, stream>>>(rowsum_u, pos_u, rowsum_i, pos_i, accum,
                                         (float*)d_out);
}

// Round 4
// 767.460 us; speedup vs baseline: 1.0036x; 1.0036x over previous
//
#include <hip/hip_runtime.h>
#include <hip/hip_bf16.h>
#include <math.h>

#define UCNT 50000
#define ICNT 25000
#define NNODE 75000
#define DDIM 64
#define BB 4096
#define EPS_C 0.2f
#define INV_TEMP 5.0f
#define NB_SCAN ((NNODE + 255) / 256)   // 293

#define BKT_SHIFT 15
#define BKT_SLOTS (1 << BKT_SHIFT)      // 32768 slots = 128 KB csr region
#define NBKT 62                         // ceil(2e6 / 32768)
#define PCAP 128                        // LDS queue cap per bucket (mean 67, 7.5 sigma)
#define EPB 4096                        // edges per partition block

__device__ __forceinline__ float wave_sum(float x) {
#pragma unroll
  for (int m = 32; m >= 1; m >>= 1) x += __shfl_xor(x, m, 64);
  return x;
}

// ---------------- init ----------------
__global__ void init_kernel(int* __restrict__ counts, int* __restrict__ gcur,
                            float* __restrict__ rowsum_u, float* __restrict__ rowsum_i,
                            float* __restrict__ accum) {
  int i = blockIdx.x * blockDim.x + threadIdx.x;
  if (i < NNODE) counts[i] = 0;
  if (i < NBKT) gcur[i] = i << BKT_SHIFT;
  if (i < BB) { rowsum_u[i] = 0.f; rowsum_i[i] = 0.f; }
  if (i < 2) accum[i] = 0.f;
}

// ---------------- histogram + per-edge rank (coalesced rank write) ----------------
__global__ void hist_rank_kernel(const int* __restrict__ src, int* __restrict__ counts,
                                 int* __restrict__ rank, int ne) {
  int i = blockIdx.x * blockDim.x + threadIdx.x;
  int stride = gridDim.x * blockDim.x;
  for (; i < ne; i += stride) rank[i] = atomicAdd(&counts[src[i]], 1);
}

// ---------------- hierarchical scan: pass 1 — per-block sums ----------------
__global__ __launch_bounds__(256) void blocksum_kernel(const int* __restrict__ counts,
                                                       int* __restrict__ bsum, int n) {
  int t = threadIdx.x;
  int i = blockIdx.x * 256 + t;
  int c = (i < n) ? counts[i] : 0;
#pragma unroll
  for (int m = 32; m >= 1; m >>= 1) c += __shfl_xor(c, m, 64);
  __shared__ int ws[4];
  if ((t & 63) == 0) ws[t >> 6] = c;
  __syncthreads();
  if (t == 0) bsum[blockIdx.x] = ws[0] + ws[1] + ws[2] + ws[3];
}

// ---------------- hierarchical scan: pass 2 — scan the 293 block sums ----------------
__global__ __launch_bounds__(512) void bscan_kernel(const int* __restrict__ bsum,
                                                    int* __restrict__ boff, int nb) {
  int t = threadIdx.x;
  int lane = t & 63, wid = t >> 6;
  int c = (t < nb) ? bsum[t] : 0;
  int v = c;
#pragma unroll
  for (int d = 1; d < 64; d <<= 1) {
    int u = __shfl_up(v, d, 64);
    if (lane >= d) v += u;
  }
  __shared__ int ws[8], wo[8];
  if (lane == 63) ws[wid] = v;
  __syncthreads();
  if (t == 0) {
    int run = 0;
    for (int k = 0; k < 8; ++k) { wo[k] = run; run += ws[k]; }
  }
  __syncthreads();
  if (t < nb) boff[t] = v - c + wo[wid];
}

// ---------------- hierarchical scan: pass 3 — local scan + offset ----------------
__global__ __launch_bounds__(256) void scanout_kernel(const int* __restrict__ counts,
                                                      const int* __restrict__ boff,
                                                      int* __restrict__ row_ptr, int n) {
  int t = threadIdx.x;
  int lane = t & 63, wid = t >> 6;
  int i = blockIdx.x * 256 + t;
  int c = (i < n) ? counts[i] : 0;
  int v = c;
#pragma unroll
  for (int d = 1; d < 64; d <<= 1) {
    int u = __shfl_up(v, d, 64);
    if (lane >= d) v += u;
  }
  __shared__ int ws[4], wo[4];
  if (lane == 63) ws[wid] = v;
  __syncthreads();
  if (t == 0) {
    int run = 0;
    for (int k = 0; k < 4; ++k) { wo[k] = run; run += ws[k]; }
  }
  __syncthreads();
  int excl = v - c + wo[wid] + boff[blockIdx.x];
  if (i < n) {
    row_ptr[i] = excl;
    if (i == n - 1) row_ptr[n] = excl + c;
  }
}

// ---------------- partition: bin (slot,dst) into bucket FIFOs via LDS ----------------
__global__ __launch_bounds__(256) void partition_kernel(
    const int* __restrict__ src, const int* __restrict__ dst, const int* __restrict__ rank,
    const int* __restrict__ row_ptr, unsigned long long* __restrict__ gfifo,
    int* __restrict__ gcur, int* __restrict__ csr_dst, int ne) {
  __shared__ unsigned long long q[NBKT * PCAP];
  __shared__ int lcnt[NBKT];
  int t = threadIdx.x;
  for (int b = t; b < NBKT; b += 256) lcnt[b] = 0;
  __syncthreads();
  int base = blockIdx.x * EPB;
  int lim = min(base + EPB, ne);
  for (int i = base + t; i < lim; i += 256) {
    int s = src[i];
    int slot = row_ptr[s] + rank[i];
    int d = dst[i];
    int b = slot >> BKT_SHIFT;
    if (b < NBKT) {
      int pos = atomicAdd(&lcnt[b], 1);
      if (pos < PCAP)
        q[b * PCAP + pos] = ((unsigned long long)(unsigned)slot << 32) | (unsigned)d;
      else
        csr_dst[slot] = d;            // statistically-never overflow fallback
    } else {
      csr_dst[slot] = d;              // out-of-range guard (never for E2<=2,031,616)
    }
  }
  __syncthreads();
  int lane = t & 63, w = t >> 6;
  for (int b = w; b < NBKT; b += 4) {
    int cnt = min(lcnt[b], PCAP);
    int gbase = 0;
    if (lane == 0 && cnt > 0) gbase = atomicAdd(&gcur[b], cnt);
    gbase = __shfl(gbase, 0, 64);
    for (int j = lane; j < cnt; j += 64) gfifo[gbase + j] = q[b * PCAP + j];
  }
}

// ---------------- scatter2: one block per bucket, region-local writes ----------------
__global__ __launch_bounds__(256) void scatter2_kernel(const unsigned long long* __restrict__ gfifo,
                                                       const int* __restrict__ gcur,
                                                       int* __restrict__ csr_dst) {
  int b = blockIdx.x;
  int start = b << BKT_SHIFT;
  int end = gcur[b];
  for (int j = start + threadIdx.x; j < end; j += 256) {
    unsigned long long e = gfifo[j];
    csr_dst[e >> 32] = (int)(unsigned)e;
  }
}

// ---------------- prescale: y_init[n] = table[n] * rsqrt(max(deg,1)) ----------------
__global__ __launch_bounds__(256) void prescale_kernel(const float* __restrict__ ut,
                                                       const float* __restrict__ it,
                                                       const int* __restrict__ counts,
                                                       float* __restrict__ y) {
  int idx = blockIdx.x * 256 + threadIdx.x;   // one float4 per thread
  if (idx >= NNODE * 16) return;
  int n = idx >> 4;
  float sc = rsqrtf(fmaxf((float)counts[n], 1.f));
  const float* srcp = (n < UCNT) ? (ut + (size_t)n * DDIM)
                                 : (it + (size_t)(n - UCNT) * DDIM);
  float4 v = *(const float4*)(srcp + (idx & 15) * 4);
  v.x *= sc; v.y *= sc; v.z *= sc; v.w *= sc;
  *(float4*)((float*)y + (size_t)idx * 4) = v;
}

// ---------------- SpMM (gather-sum of prescaled rows) + noise ----------------
__global__ __launch_bounds__(256) void spmm_kernel(const float* __restrict__ y_in,
                                                   const int* __restrict__ row_ptr,
                                                   const int* __restrict__ csr_dst,
                                                   const int* __restrict__ counts,
                                                   const float* __restrict__ noise,
                                                   float* __restrict__ y_out) {
  int wave = blockIdx.x * 4 + (threadIdx.x >> 6);
  int lane = threadIdx.x & 63;
  if (wave >= NNODE) return;
  int r = wave;
  int beg = row_ptr[r], endp = row_ptr[r + 1];
  int g = lane >> 4, l16 = lane & 15;
  float4 acc = {0.f, 0.f, 0.f, 0.f};
  for (int e0 = beg; e0 < endp; e0 += 64) {
    int e = e0 + lane;
    int d = (e < endp) ? csr_dst[e] : 0;
    int cnt = min(64, endp - e0);
    for (int j = 0; j < cnt; j += 4) {
      int dj = __shfl(d, j + g, 64);
      if (j + g < cnt) {    // group-uniform branch
        float4 xv = *(const float4*)(y_in + (size_t)dj * DDIM + l16 * 4);
        acc.x += xv.x; acc.y += xv.y; acc.z += xv.z; acc.w += xv.w;
      }
    }
  }
#pragma unroll
  for (int m = 16; m <= 32; m <<= 1) {
    acc.x += __shfl_xor(acc.x, m, 64);
    acc.y += __shfl_xor(acc.y, m, 64);
    acc.z += __shfl_xor(acc.z, m, 64);
    acc.w += __shfl_xor(acc.w, m, 64);
  }
  float sc = rsqrtf(fmaxf((float)counts[r], 1.f));
  acc.x *= sc; acc.y *= sc; acc.z *= sc; acc.w *= sc;   // x (pre-noise)
  float4 nf = *(const float4*)(noise + (size_t)r * DDIM + l16 * 4);
  float ss = nf.x * nf.x + nf.y * nf.y + nf.z * nf.z + nf.w * nf.w;
#pragma unroll
  for (int m = 1; m <= 8; m <<= 1) ss += __shfl_xor(ss, m, 64);  // 16-lane group = row
  float inv = EPS_C / fmaxf(sqrtf(ss), 1e-12f);
  float4 o;
  o.x = acc.x + ((acc.x > 0.f) ? 1.f : ((acc.x < 0.f) ? -1.f : 0.f)) * nf.x * inv;
  o.y = acc.y + ((acc.y > 0.f) ? 1.f : ((acc.y < 0.f) ? -1.f : 0.f)) * nf.y * inv;
  o.z = acc.z + ((acc.z > 0.f) ? 1.f : ((acc.z < 0.f) ? -1.f : 0.f)) * nf.z * inv;
  o.w = acc.w + ((acc.w > 0.f) ? 1.f : ((acc.w < 0.f) ? -1.f : 0.f)) * nf.w * inv;
  o.x *= sc; o.y *= sc; o.z *= sc; o.w *= sc;           // store y = x * sc
  if (g == 0) *(float4*)(y_out + (size_t)r * DDIM + l16 * 4) = o;
}

// ---------------- batch gather: BPR, reg, normalized InfoNCE inputs ----------------
__global__ __launch_bounds__(256) void batch_kernel(
    const float* __restrict__ yb0, const float* __restrict__ yb1, const float* __restrict__ yb2,
    const float* __restrict__ ut, const float* __restrict__ it,
    const int* __restrict__ counts,
    const int* __restrict__ user, const int* __restrict__ pos, const int* __restrict__ neg,
    float* __restrict__ z1u, float* __restrict__ z2u,
    float* __restrict__ z1i, float* __restrict__ z2i,
    float* __restrict__ pos_u, float* __restrict__ pos_i, float* __restrict__ accum) {
  int wave = blockIdx.x * (blockDim.x >> 6) + (threadIdx.x >> 6);
  int lane = threadIdx.x & 63;
  if (wave >= BB) return;
  int b = wave;
  int iu = user[b], ip = pos[b], ing = neg[b];
  float s_u = sqrtf(fmaxf((float)counts[iu], 1.f));
  float s_p = sqrtf(fmaxf((float)counts[UCNT + ip], 1.f));
  float s_n = sqrtf(fmaxf((float)counts[UCNT + ing], 1.f));
  size_t ru = (size_t)iu * DDIM + lane;
  size_t rp = (size_t)(UCNT + ip) * DDIM + lane;
  size_t rn = (size_t)(UCNT + ing) * DDIM + lane;
  float cu = yb0[ru] * s_u;        // x_cl user row
  float ci = yb0[rp] * s_p;        // x_cl positive-item row
  float ue = (cu + (yb1[ru] + yb2[ru]) * s_u) * (1.f / 3.f);
  float pe = (ci + (yb1[rp] + yb2[rp]) * s_p) * (1.f / 3.f);
  float ne = (yb0[rn] + yb1[rn] + yb2[rn]) * s_n * (1.f / 3.f);

  float ps = wave_sum(ue * pe);
  float ns = wave_sum(ue * ne);
  float x = ns - ps;
  float sp = fmaxf(x, 0.f) + log1pf(expf(-fabsf(x)));

  float eu = ut[(size_t)iu * DDIM + lane];
  float ep = it[(size_t)ip * DDIM + lane];
  float en = it[(size_t)ing * DDIM + lane];
  float rr = wave_sum(eu * eu + ep * ep + en * en);
  if (lane == 0) { atomicAdd(&accum[0], sp); atomicAdd(&accum[1], rr); }

  float n1 = fmaxf(sqrtf(wave_sum(cu * cu)), 1e-12f);
  float n2 = fmaxf(sqrtf(wave_sum(ue * ue)), 1e-12f);
  float d12 = wave_sum(cu * ue);
  z1u[(size_t)b * DDIM + lane] = cu / n1;
  z2u[(size_t)b * DDIM + lane] = ue / n2;
  if (lane == 0) pos_u[b] = d12 / (n1 * n2) * INV_TEMP;

  float m1 = fmaxf(sqrtf(wave_sum(ci * ci)), 1e-12f);
  float m2 = fmaxf(sqrtf(wave_sum(pe * pe)), 1e-12f);
  float e12 = wave_sum(ci * pe);
  z1i[(size_t)b * DDIM + lane] = ci / m1;
  z2i[(size_t)b * DDIM + lane] = pe / m2;
  if (lane == 0) pos_i[b] = e12 / (m1 * m2) * INV_TEMP;
}

// ---------------- InfoNCE similarity tile ----------------
__global__ __launch_bounds__(256) void infonce_kernel(const float* __restrict__ Z1,
                                                      const float* __restrict__ Z2,
                                                      float* __restrict__ rowsum) {
  __shared__ float S1[64][65];
  __shared__ float S2[64][65];
  __shared__ float red[64][17];
  int t = threadIdx.x;
  int i0 = blockIdx.y * 64, j0 = blockIdx.x * 64;
#pragma unroll
  for (int rep = 0; rep < 4; ++rep) {
    int vlin = rep * 256 + t;       // float4 index in 64x16
    int row = vlin >> 4;
    int c4 = (vlin & 15) * 4;
    float4 a = *(const float4*)(Z1 + (size_t)(i0 + row) * DDIM + c4);
    S1[c4 + 0][row] = a.x; S1[c4 + 1][row] = a.y; S1[c4 + 2][row] = a.z; S1[c4 + 3][row] = a.w;
    float4 b = *(const float4*)(Z2 + (size_t)(j0 + row) * DDIM + c4);
    S2[c4 + 0][row] = b.x; S2[c4 + 1][row] = b.y; S2[c4 + 2][row] = b.z; S2[c4 + 3][row] = b.w;
  }
  __syncthreads();
  int ti = (t & 15) * 4;
  int tj = (t >> 4) * 4;
  float acc[4][4] = {};
  for (int k = 0; k < 64; ++k) {
    float4 av = *(const float4*)&S1[k][ti];
    float4 bv = *(const float4*)&S2[k][tj];
    float a[4] = {av.x, av.y, av.z, av.w};
    float b[4] = {bv.x, bv.y, bv.z, bv.w};
#pragma unroll
    for (int r = 0; r < 4; ++r)
#pragma unroll
      for (int c = 0; c < 4; ++c) acc[r][c] += a[r] * b[c];
  }
  int q = t >> 4;
#pragma unroll
  for (int r = 0; r < 4; ++r) {
    float s = __expf(acc[r][0] * INV_TEMP) + __expf(acc[r][1] * INV_TEMP) +
              __expf(acc[r][2] * INV_TEMP) + __expf(acc[r][3] * INV_TEMP);
    red[ti + r][q] = s;
  }
  __syncthreads();
  if (t < 64) {
    float tot = 0.f;
#pragma unroll
    for (int q2 = 0; q2 < 16; ++q2) tot += red[t][q2];
    atomicAdd(&rowsum[i0 + t], tot);
  }
}

// ---------------- finalize ----------------
__global__ __launch_bounds__(256) void finalize_kernel(const float* __restrict__ rowsum_u,
                                                       const float* __restrict__ pos_u,
                                                       const float* __restrict__ rowsum_i,
                                                       const float* __restrict__ pos_i,
                                                       const float* __restrict__ accum,
                                                       float* __restrict__ out) {
  int t = threadIdx.x;
  float su = 0.f, si = 0.f;
  for (int i = t; i < BB; i += 256) {
    su += logf(rowsum_u[i]) - pos_u[i];
    si += logf(rowsum_i[i]) - pos_i[i];
  }
  su = wave_sum(su);
  si = wave_sum(si);
  __shared__ float sh[8];
  int lane = t & 63, wid = t >> 6;
  if (lane == 0) { sh[wid] = su; sh[4 + wid] = si; }
  __syncthreads();
  if (t == 0) {
    float SU = sh[0] + sh[1] + sh[2] + sh[3];
    float SI = sh[4] + sh[5] + sh[6] + sh[7];
    out[0] = accum[0] * (1.f / BB);
    out[1] = 1e-4f * 0.5f * accum[1] * (1.f / BB);
    out[2] = 0.2f * ((SU + SI) * (1.f / BB));
  }
}

extern "C" void kernel_launch(void* const* d_in, const int* in_sizes, int n_in,
                              void* d_out, int out_size, void* d_ws, size_t ws_size,
                              hipStream_t stream) {
  const float* user_table = (const float*)d_in[0];
  const float* item_table = (const float*)d_in[1];
  const float* noise      = (const float*)d_in[3];
  const int*   edge_src   = (const int*)d_in[4];
  const int*   edge_dst   = (const int*)d_in[5];
  const int*   user       = (const int*)d_in[6];
  const int*   positive   = (const int*)d_in[7];
  const int*   negative   = (const int*)d_in[8];
  const int E2 = in_sizes[2];  // 2,000,000

  char* w = (char*)d_ws;
  auto alloc = [&](size_t bytes) -> void* {
    void* p = (void*)w;
    w += (bytes + 255) & ~(size_t)255;
    return p;
  };
  int*   counts   = (int*)alloc((size_t)NNODE * 4);
  int*   row_ptr  = (int*)alloc((size_t)(NNODE + 1) * 4);
  int*   rank     = (int*)alloc((size_t)E2 * 4);
  int*   bsum     = (int*)alloc((size_t)NB_SCAN * 4);
  int*   boff     = (int*)alloc((size_t)NB_SCAN * 4);
  int*   gcur     = (int*)alloc((size_t)NBKT * 4);
  int*   csr_dst  = (int*)alloc((size_t)E2 * 4);
  unsigned long long* gfifo = (unsigned long long*)alloc((size_t)E2 * 8);
  float* y_init   = (float*)alloc((size_t)NNODE * DDIM * 4);
  float* yb0      = (float*)alloc((size_t)NNODE * DDIM * 4);
  float* yb1      = (float*)alloc((size_t)NNODE * DDIM * 4);
  float* yb2      = (float*)alloc((size_t)NNODE * DDIM * 4);
  float* z1u      = (float*)alloc((size_t)BB * DDIM * 4);
  float* z2u      = (float*)alloc((size_t)BB * DDIM * 4);
  float* z1i      = (float*)alloc((size_t)BB * DDIM * 4);
  float* z2i      = (float*)alloc((size_t)BB * DDIM * 4);
  float* pos_u    = (float*)alloc((size_t)BB * 4);
  float* pos_i    = (float*)alloc((size_t)BB * 4);
  float* rowsum_u = (float*)alloc((size_t)BB * 4);
  float* rowsum_i = (float*)alloc((size_t)BB * 4);
  float* accum    = (float*)alloc(256);

  init_kernel<<<(NNODE + 255) / 256, 256, 0, stream>>>(counts, gcur, rowsum_u, rowsum_i, accum);
  hist_rank_kernel<<<2048, 256, 0, stream>>>(edge_src, counts, rank, E2);
  blocksum_kernel<<<NB_SCAN, 256, 0, stream>>>(counts, bsum, NNODE);
  bscan_kernel<<<1, 512, 0, stream>>>(bsum, boff, NB_SCAN);
  scanout_kernel<<<NB_SCAN, 256, 0, stream>>>(counts, boff, row_ptr, NNODE);
  partition_kernel<<<(E2 + EPB - 1) / EPB, 256, 0, stream>>>(edge_src, edge_dst, rank,
                                                             row_ptr, gfifo, gcur, csr_dst, E2);
  scatter2_kernel<<<NBKT, 256, 0, stream>>>(gfifo, gcur, csr_dst);
  prescale_kernel<<<(NNODE * 16 + 255) / 256, 256, 0, stream>>>(user_table, item_table,
                                                                counts, y_init);
  const int spmm_blocks = (NNODE + 3) / 4;  // 4 waves per 256-thread block
  spmm_kernel<<<spmm_blocks, 256, 0, stream>>>(y_init, row_ptr, csr_dst, counts,
                                               noise + (size_t)0 * NNODE * DDIM, yb0);
  spmm_kernel<<<spmm_blocks, 256, 0, stream>>>(yb0, row_ptr, csr_dst, counts,
                                               noise + (size_t)1 * NNODE * DDIM, yb1);
  spmm_kernel<<<spmm_blocks, 256, 0, stream>>>(yb1, row_ptr, csr_dst, counts,
                                               noise + (size_t)2 * NNODE * DDIM, yb2);
  batch_kernel<<<BB / 4, 256, 0, stream>>>(yb0, yb1, yb2, user_table, item_table, counts,
                                           user, positive, negative,
                                           z1u, z2u, z1i, z2i, pos_u, pos_i, accum);
  dim3 ig(BB / 64, BB / 64);
  infonce_kernel<<<ig, 256, 0, stream>>>(z1u, z2u, rowsum_u);
  infonce_kernel<<<ig, 256, 0, stream>>>(z1i, z2i, rowsum_i);
  finalize_kernel<<<1, 256, 0, stream>>>(rowsum_u, pos_u, rowsum_i, pos_i, accum,
                                         (float*)d_out);
}

// Round 5
// 672.431 us; speedup vs baseline: 1.1454x; 1.1413x over previous
//
#include <hip/hip_runtime.h>
#include <hip/hip_bf16.h>
#include <math.h>

#define UCNT 50000
#define ICNT 25000
#define NNODE 75000
#define DDIM 64
#define BB 4096
#define EPS_C 0.2f
#define INV_TEMP 5.0f
#define NB_SCAN ((NNODE + 255) / 256)   // 293

#define BKT_SHIFT 15
#define BKT_SLOTS (1 << BKT_SHIFT)      // 32768 slots = 128 KB csr region
#define NBKT 62                         // ceil(2e6 / 32768)
#define PCAP 128                        // LDS queue cap per bucket
#define EPB 4096                        // edges per partition block
#define NJT (BB / 64)                   // 64 j-tiles in infonce

__device__ __forceinline__ float wave_sum(float x) {
#pragma unroll
  for (int m = 32; m >= 1; m >>= 1) x += __shfl_xor(x, m, 64);
  return x;
}

// ---------------- init ----------------
__global__ void init_kernel(int* __restrict__ counts, int* __restrict__ gcur) {
  int i = blockIdx.x * blockDim.x + threadIdx.x;
  if (i < NNODE) counts[i] = 0;
  if (i < NBKT) gcur[i] = i << BKT_SHIFT;
}

// ---------------- histogram + per-edge rank (coalesced rank write) ----------------
__global__ void hist_rank_kernel(const int* __restrict__ src, int* __restrict__ counts,
                                 int* __restrict__ rank, int ne) {
  int i = blockIdx.x * blockDim.x + threadIdx.x;
  int stride = gridDim.x * blockDim.x;
  for (; i < ne; i += stride) rank[i] = atomicAdd(&counts[src[i]], 1);
}

// ---------------- hierarchical scan: pass 1 — per-block sums ----------------
__global__ __launch_bounds__(256) void blocksum_kernel(const int* __restrict__ counts,
                                                       int* __restrict__ bsum, int n) {
  int t = threadIdx.x;
  int i = blockIdx.x * 256 + t;
  int c = (i < n) ? counts[i] : 0;
#pragma unroll
  for (int m = 32; m >= 1; m >>= 1) c += __shfl_xor(c, m, 64);
  __shared__ int ws[4];
  if ((t & 63) == 0) ws[t >> 6] = c;
  __syncthreads();
  if (t == 0) bsum[blockIdx.x] = ws[0] + ws[1] + ws[2] + ws[3];
}

// ---------------- hierarchical scan: pass 2 — scan the 293 block sums ----------------
__global__ __launch_bounds__(512) void bscan_kernel(const int* __restrict__ bsum,
                                                    int* __restrict__ boff, int nb) {
  int t = threadIdx.x;
  int lane = t & 63, wid = t >> 6;
  int c = (t < nb) ? bsum[t] : 0;
  int v = c;
#pragma unroll
  for (int d = 1; d < 64; d <<= 1) {
    int u = __shfl_up(v, d, 64);
    if (lane >= d) v += u;
  }
  __shared__ int ws[8], wo[8];
  if (lane == 63) ws[wid] = v;
  __syncthreads();
  if (t == 0) {
    int run = 0;
    for (int k = 0; k < 8; ++k) { wo[k] = run; run += ws[k]; }
  }
  __syncthreads();
  if (t < nb) boff[t] = v - c + wo[wid];
}

// ---------------- hierarchical scan: pass 3 — local scan + offset ----------------
__global__ __launch_bounds__(256) void scanout_kernel(const int* __restrict__ counts,
                                                      const int* __restrict__ boff,
                                                      int* __restrict__ row_ptr, int n) {
  int t = threadIdx.x;
  int lane = t & 63, wid = t >> 6;
  int i = blockIdx.x * 256 + t;
  int c = (i < n) ? counts[i] : 0;
  int v = c;
#pragma unroll
  for (int d = 1; d < 64; d <<= 1) {
    int u = __shfl_up(v, d, 64);
    if (lane >= d) v += u;
  }
  __shared__ int ws[4], wo[4];
  if (lane == 63) ws[wid] = v;
  __syncthreads();
  if (t == 0) {
    int run = 0;
    for (int k = 0; k < 4; ++k) { wo[k] = run; run += ws[k]; }
  }
  __syncthreads();
  int excl = v - c + wo[wid] + boff[blockIdx.x];
  if (i < n) {
    row_ptr[i] = excl;
    if (i == n - 1) row_ptr[n] = excl + c;
  }
}

// ---------------- partition: bin (slot,dst) into bucket FIFOs via LDS ----------------
__global__ __launch_bounds__(256) void partition_kernel(
    const int* __restrict__ src, const int* __restrict__ dst, const int* __restrict__ rank,
    const int* __restrict__ row_ptr, unsigned long long* __restrict__ gfifo,
    int* __restrict__ gcur, int* __restrict__ csr_dst, int ne) {
  __shared__ unsigned long long q[NBKT * PCAP];
  __shared__ int lcnt[NBKT];
  int t = threadIdx.x;
  for (int b = t; b < NBKT; b += 256) lcnt[b] = 0;
  __syncthreads();
  int base = blockIdx.x * EPB;
  int lim = min(base + EPB, ne);
  for (int i = base + t; i < lim; i += 256) {
    int s = src[i];
    int slot = row_ptr[s] + rank[i];
    int d = dst[i];
    int b = slot >> BKT_SHIFT;
    if (b < NBKT) {
      int pos = atomicAdd(&lcnt[b], 1);
      if (pos < PCAP)
        q[b * PCAP + pos] = ((unsigned long long)(unsigned)slot << 32) | (unsigned)d;
      else
        csr_dst[slot] = d;            // statistically-never overflow fallback
    } else {
      csr_dst[slot] = d;              // out-of-range guard
    }
  }
  __syncthreads();
  int lane = t & 63, w = t >> 6;
  for (int b = w; b < NBKT; b += 4) {
    int cnt = min(lcnt[b], PCAP);
    int gbase = 0;
    if (lane == 0 && cnt > 0) gbase = atomicAdd(&gcur[b], cnt);
    gbase = __shfl(gbase, 0, 64);
    for (int j = lane; j < cnt; j += 64) gfifo[gbase + j] = q[b * PCAP + j];
  }
}

// ---------------- scatter2: one block per bucket, region-local writes ----------------
__global__ __launch_bounds__(256) void scatter2_kernel(const unsigned long long* __restrict__ gfifo,
                                                       const int* __restrict__ gcur,
                                                       int* __restrict__ csr_dst) {
  int b = blockIdx.x;
  int start = b << BKT_SHIFT;
  int end = gcur[b];
  for (int j = start + threadIdx.x; j < end; j += 256) {
    unsigned long long e = gfifo[j];
    csr_dst[e >> 32] = (int)(unsigned)e;
  }
}

// ---------------- prescale: y_init[n] = table[n] * rsqrt(max(deg,1)) ----------------
__global__ __launch_bounds__(256) void prescale_kernel(const float* __restrict__ ut,
                                                       const float* __restrict__ it,
                                                       const int* __restrict__ counts,
                                                       float* __restrict__ y) {
  int idx = blockIdx.x * 256 + threadIdx.x;   // one float4 per thread
  if (idx >= NNODE * 16) return;
  int n = idx >> 4;
  float sc = rsqrtf(fmaxf((float)counts[n], 1.f));
  const float* srcp = (n < UCNT) ? (ut + (size_t)n * DDIM)
                                 : (it + (size_t)(n - UCNT) * DDIM);
  float4 v = *(const float4*)(srcp + (idx & 15) * 4);
  v.x *= sc; v.y *= sc; v.z *= sc; v.w *= sc;
  *(float4*)((float*)y + (size_t)idx * 4) = v;
}

// ---------------- SpMM (gather-sum of prescaled rows) + noise ----------------
__global__ __launch_bounds__(256) void spmm_kernel(const float* __restrict__ y_in,
                                                   const int* __restrict__ row_ptr,
                                                   const int* __restrict__ csr_dst,
                                                   const int* __restrict__ counts,
                                                   const float* __restrict__ noise,
                                                   float* __restrict__ y_out) {
  int wave = blockIdx.x * 4 + (threadIdx.x >> 6);
  int lane = threadIdx.x & 63;
  if (wave >= NNODE) return;
  int r = wave;
  int beg = row_ptr[r], endp = row_ptr[r + 1];
  int g = lane >> 4, l16 = lane & 15;
  float4 acc = {0.f, 0.f, 0.f, 0.f};
  for (int e0 = beg; e0 < endp; e0 += 64) {
    int e = e0 + lane;
    int d = (e < endp) ? csr_dst[e] : 0;
    int cnt = min(64, endp - e0);
    for (int j = 0; j < cnt; j += 4) {
      int dj = __shfl(d, j + g, 64);
      if (j + g < cnt) {    // group-uniform branch
        float4 xv = *(const float4*)(y_in + (size_t)dj * DDIM + l16 * 4);
        acc.x += xv.x; acc.y += xv.y; acc.z += xv.z; acc.w += xv.w;
      }
    }
  }
#pragma unroll
  for (int m = 16; m <= 32; m <<= 1) {
    acc.x += __shfl_xor(acc.x, m, 64);
    acc.y += __shfl_xor(acc.y, m, 64);
    acc.z += __shfl_xor(acc.z, m, 64);
    acc.w += __shfl_xor(acc.w, m, 64);
  }
  float sc = rsqrtf(fmaxf((float)counts[r], 1.f));
  acc.x *= sc; acc.y *= sc; acc.z *= sc; acc.w *= sc;   // x (pre-noise)
  float4 nf = *(const float4*)(noise + (size_t)r * DDIM + l16 * 4);
  float ss = nf.x * nf.x + nf.y * nf.y + nf.z * nf.z + nf.w * nf.w;
#pragma unroll
  for (int m = 1; m <= 8; m <<= 1) ss += __shfl_xor(ss, m, 64);  // 16-lane group = row
  float inv = EPS_C / fmaxf(sqrtf(ss), 1e-12f);
  float4 o;
  o.x = acc.x + ((acc.x > 0.f) ? 1.f : ((acc.x < 0.f) ? -1.f : 0.f)) * nf.x * inv;
  o.y = acc.y + ((acc.y > 0.f) ? 1.f : ((acc.y < 0.f) ? -1.f : 0.f)) * nf.y * inv;
  o.z = acc.z + ((acc.z > 0.f) ? 1.f : ((acc.z < 0.f) ? -1.f : 0.f)) * nf.z * inv;
  o.w = acc.w + ((acc.w > 0.f) ? 1.f : ((acc.w < 0.f) ? -1.f : 0.f)) * nf.w * inv;
  o.x *= sc; o.y *= sc; o.z *= sc; o.w *= sc;           // store y = x * sc
  if (g == 0) *(float4*)(y_out + (size_t)r * DDIM + l16 * 4) = o;
}

// ---------------- batch gather: BPR, reg, normalized InfoNCE inputs ----------------
// NO device atomics: per-wave results stored to sp_arr / rr_arr (summed in finalize).
__global__ __launch_bounds__(256) void batch_kernel(
    const float* __restrict__ yb0, const float* __restrict__ yb1, const float* __restrict__ yb2,
    const float* __restrict__ ut, const float* __restrict__ it,
    const int* __restrict__ counts,
    const int* __restrict__ user, const int* __restrict__ pos, const int* __restrict__ neg,
    float* __restrict__ z1u, float* __restrict__ z2u,
    float* __restrict__ z1i, float* __restrict__ z2i,
    float* __restrict__ pos_u, float* __restrict__ pos_i,
    float* __restrict__ sp_arr, float* __restrict__ rr_arr) {
  int wave = blockIdx.x * (blockDim.x >> 6) + (threadIdx.x >> 6);
  int lane = threadIdx.x & 63;
  if (wave >= BB) return;
  int b = wave;
  int iu = user[b], ip = pos[b], ing = neg[b];
  float s_u = sqrtf(fmaxf((float)counts[iu], 1.f));
  float s_p = sqrtf(fmaxf((float)counts[UCNT + ip], 1.f));
  float s_n = sqrtf(fmaxf((float)counts[UCNT + ing], 1.f));
  size_t ru = (size_t)iu * DDIM + lane;
  size_t rp = (size_t)(UCNT + ip) * DDIM + lane;
  size_t rn = (size_t)(UCNT + ing) * DDIM + lane;
  float cu = yb0[ru] * s_u;        // x_cl user row
  float ci = yb0[rp] * s_p;        // x_cl positive-item row
  float ue = (cu + (yb1[ru] + yb2[ru]) * s_u) * (1.f / 3.f);
  float pe = (ci + (yb1[rp] + yb2[rp]) * s_p) * (1.f / 3.f);
  float ne = (yb0[rn] + yb1[rn] + yb2[rn]) * s_n * (1.f / 3.f);

  float ps = wave_sum(ue * pe);
  float ns = wave_sum(ue * ne);
  float x = ns - ps;
  float sp = fmaxf(x, 0.f) + log1pf(expf(-fabsf(x)));

  float eu = ut[(size_t)iu * DDIM + lane];
  float ep = it[(size_t)ip * DDIM + lane];
  float en = it[(size_t)ing * DDIM + lane];
  float rr = wave_sum(eu * eu + ep * ep + en * en);
  if (lane == 0) { sp_arr[b] = sp; rr_arr[b] = rr; }

  float n1 = fmaxf(sqrtf(wave_sum(cu * cu)), 1e-12f);
  float n2 = fmaxf(sqrtf(wave_sum(ue * ue)), 1e-12f);
  float d12 = wave_sum(cu * ue);
  z1u[(size_t)b * DDIM + lane] = cu / n1;
  z2u[(size_t)b * DDIM + lane] = ue / n2;
  if (lane == 0) pos_u[b] = d12 / (n1 * n2) * INV_TEMP;

  float m1 = fmaxf(sqrtf(wave_sum(ci * ci)), 1e-12f);
  float m2 = fmaxf(sqrtf(wave_sum(pe * pe)), 1e-12f);
  float e12 = wave_sum(ci * pe);
  z1i[(size_t)b * DDIM + lane] = ci / m1;
  z2i[(size_t)b * DDIM + lane] = pe / m2;
  if (lane == 0) pos_i[b] = e12 / (m1 * m2) * INV_TEMP;
}

// ---------------- InfoNCE similarity tile: partial per (jtile,row), NO atomics --------
__global__ __launch_bounds__(256) void infonce_kernel(const float* __restrict__ Z1,
                                                      const float* __restrict__ Z2,
                                                      float* __restrict__ rowpart) {
  __shared__ float S1[64][65];
  __shared__ float S2[64][65];
  __shared__ float red[64][17];
  int t = threadIdx.x;
  int i0 = blockIdx.y * 64, j0 = blockIdx.x * 64;
#pragma unroll
  for (int rep = 0; rep < 4; ++rep) {
    int vlin = rep * 256 + t;       // float4 index in 64x16
    int row = vlin >> 4;
    int c4 = (vlin & 15) * 4;
    float4 a = *(const float4*)(Z1 + (size_t)(i0 + row) * DDIM + c4);
    S1[c4 + 0][row] = a.x; S1[c4 + 1][row] = a.y; S1[c4 + 2][row] = a.z; S1[c4 + 3][row] = a.w;
    float4 b = *(const float4*)(Z2 + (size_t)(j0 + row) * DDIM + c4);
    S2[c4 + 0][row] = b.x; S2[c4 + 1][row] = b.y; S2[c4 + 2][row] = b.z; S2[c4 + 3][row] = b.w;
  }
  __syncthreads();
  int ti = (t & 15) * 4;
  int tj = (t >> 4) * 4;
  float acc[4][4] = {};
  for (int k = 0; k < 64; ++k) {
    float4 av = *(const float4*)&S1[k][ti];
    float4 bv = *(const float4*)&S2[k][tj];
    float a[4] = {av.x, av.y, av.z, av.w};
    float b[4] = {bv.x, bv.y, bv.z, bv.w};
#pragma unroll
    for (int r = 0; r < 4; ++r)
#pragma unroll
      for (int c = 0; c < 4; ++c) acc[r][c] += a[r] * b[c];
  }
  int q = t >> 4;
#pragma unroll
  for (int r = 0; r < 4; ++r) {
    float s = __expf(acc[r][0] * INV_TEMP) + __expf(acc[r][1] * INV_TEMP) +
              __expf(acc[r][2] * INV_TEMP) + __expf(acc[r][3] * INV_TEMP);
    red[ti + r][q] = s;
  }
  __syncthreads();
  if (t < 64) {
    float tot = 0.f;
#pragma unroll
    for (int q2 = 0; q2 < 16; ++q2) tot += red[t][q2];
    rowpart[(size_t)blockIdx.x * BB + i0 + t] = tot;   // coalesced, no atomic
  }
}

// ---------------- reduce 64 partials per row into rowsum ----------------
__global__ __launch_bounds__(256) void reduce_kernel(const float* __restrict__ rowpart_u,
                                                     const float* __restrict__ rowpart_i,
                                                     float* __restrict__ rowsum_u,
                                                     float* __restrict__ rowsum_i) {
  int i = blockIdx.x * 256 + threadIdx.x;   // row index
  const float* src = blockIdx.y ? rowpart_i : rowpart_u;
  float s = 0.f;
#pragma unroll 8
  for (int jb = 0; jb < NJT; ++jb) s += src[(size_t)jb * BB + i];
  if (blockIdx.y) rowsum_i[i] = s; else rowsum_u[i] = s;
}

// ---------------- finalize ----------------
__global__ __launch_bounds__(256) void finalize_kernel(const float* __restrict__ rowsum_u,
                                                       const float* __restrict__ pos_u,
                                                       const float* __restrict__ rowsum_i,
                                                       const float* __restrict__ pos_i,
                                                       const float* __restrict__ sp_arr,
                                                       const float* __restrict__ rr_arr,
                                                       float* __restrict__ out) {
  int t = threadIdx.x;
  float su = 0.f, si = 0.f, sb = 0.f, sr = 0.f;
  for (int i = t; i < BB; i += 256) {
    su += logf(rowsum_u[i]) - pos_u[i];
    si += logf(rowsum_i[i]) - pos_i[i];
    sb += sp_arr[i];
    sr += rr_arr[i];
  }
  su = wave_sum(su);
  si = wave_sum(si);
  sb = wave_sum(sb);
  sr = wave_sum(sr);
  __shared__ float sh[16];
  int lane = t & 63, wid = t >> 6;
  if (lane == 0) { sh[wid] = su; sh[4 + wid] = si; sh[8 + wid] = sb; sh[12 + wid] = sr; }
  __syncthreads();
  if (t == 0) {
    float SU = sh[0] + sh[1] + sh[2] + sh[3];
    float SI = sh[4] + sh[5] + sh[6] + sh[7];
    float SB = sh[8] + sh[9] + sh[10] + sh[11];
    float SR = sh[12] + sh[13] + sh[14] + sh[15];
    out[0] = SB * (1.f / BB);
    out[1] = 1e-4f * 0.5f * SR * (1.f / BB);
    out[2] = 0.2f * ((SU + SI) * (1.f / BB));
  }
}

extern "C" void kernel_launch(void* const* d_in, const int* in_sizes, int n_in,
                              void* d_out, int out_size, void* d_ws, size_t ws_size,
                              hipStream_t stream) {
  const float* user_table = (const float*)d_in[0];
  const float* item_table = (const float*)d_in[1];
  const float* noise      = (const float*)d_in[3];
  const int*   edge_src   = (const int*)d_in[4];
  const int*   edge_dst   = (const int*)d_in[5];
  const int*   user       = (const int*)d_in[6];
  const int*   positive   = (const int*)d_in[7];
  const int*   negative   = (const int*)d_in[8];
  const int E2 = in_sizes[2];  // 2,000,000

  char* w = (char*)d_ws;
  auto alloc = [&](size_t bytes) -> void* {
    void* p = (void*)w;
    w += (bytes + 255) & ~(size_t)255;
    return p;
  };
  int*   counts   = (int*)alloc((size_t)NNODE * 4);
  int*   row_ptr  = (int*)alloc((size_t)(NNODE + 1) * 4);
  int*   rank     = (int*)alloc((size_t)E2 * 4);
  int*   bsum     = (int*)alloc((size_t)NB_SCAN * 4);
  int*   boff     = (int*)alloc((size_t)NB_SCAN * 4);
  int*   gcur     = (int*)alloc((size_t)NBKT * 4);
  int*   csr_dst  = (int*)alloc((size_t)E2 * 4);
  unsigned long long* gfifo = (unsigned long long*)alloc((size_t)E2 * 8);
  float* y_init   = (float*)alloc((size_t)NNODE * DDIM * 4);
  float* yb0      = (float*)alloc((size_t)NNODE * DDIM * 4);
  float* yb1      = (float*)alloc((size_t)NNODE * DDIM * 4);
  float* yb2      = (float*)alloc((size_t)NNODE * DDIM * 4);
  float* z1u      = (float*)alloc((size_t)BB * DDIM * 4);
  float* z2u      = (float*)alloc((size_t)BB * DDIM * 4);
  float* z1i      = (float*)alloc((size_t)BB * DDIM * 4);
  float* z2i      = (float*)alloc((size_t)BB * DDIM * 4);
  float* pos_u    = (float*)alloc((size_t)BB * 4);
  float* pos_i    = (float*)alloc((size_t)BB * 4);
  float* rowsum_u = (float*)alloc((size_t)BB * 4);
  float* rowsum_i = (float*)alloc((size_t)BB * 4);
  float* sp_arr   = (float*)alloc((size_t)BB * 4);
  float* rr_arr   = (float*)alloc((size_t)BB * 4);
  float* rowpart_u = (float*)alloc((size_t)NJT * BB * 4);
  float* rowpart_i = (float*)alloc((size_t)NJT * BB * 4);

  init_kernel<<<(NNODE + 255) / 256, 256, 0, stream>>>(counts, gcur);
  hist_rank_kernel<<<2048, 256, 0, stream>>>(edge_src, counts, rank, E2);
  blocksum_kernel<<<NB_SCAN, 256, 0, stream>>>(counts, bsum, NNODE);
  bscan_kernel<<<1, 512, 0, stream>>>(bsum, boff, NB_SCAN);
  scanout_kernel<<<NB_SCAN, 256, 0, stream>>>(counts, boff, row_ptr, NNODE);
  partition_kernel<<<(E2 + EPB - 1) / EPB, 256, 0, stream>>>(edge_src, edge_dst, rank,
                                                             row_ptr, gfifo, gcur, csr_dst, E2);
  scatter2_kernel<<<NBKT, 256, 0, stream>>>(gfifo, gcur, csr_dst);
  prescale_kernel<<<(NNODE * 16 + 255) / 256, 256, 0, stream>>>(user_table, item_table,
                                                                counts, y_init);
  const int spmm_blocks = (NNODE + 3) / 4;  // 4 waves per 256-thread block
  spmm_kernel<<<spmm_blocks, 256, 0, stream>>>(y_init, row_ptr, csr_dst, counts,
                                               noise + (size_t)0 * NNODE * DDIM, yb0);
  spmm_kernel<<<spmm_blocks, 256, 0, stream>>>(yb0, row_ptr, csr_dst, counts,
                                               noise + (size_t)1 * NNODE * DDIM, yb1);
  spmm_kernel<<<spmm_blocks, 256, 0, stream>>>(yb1, row_ptr, csr_dst, counts,
                                               noise + (size_t)2 * NNODE * DDIM, yb2);
  batch_kernel<<<BB / 4, 256, 0, stream>>>(yb0, yb1, yb2, user_table, item_table, counts,
                                           user, positive, negative,
                                           z1u, z2u, z1i, z2i, pos_u, pos_i, sp_arr, rr_arr);
  dim3 ig(NJT, NJT);
  infonce_kernel<<<ig, 256, 0, stream>>>(z1u, z2u, rowpart_u);
  infonce_kernel<<<ig, 256, 0, stream>>>(z1i, z2i, rowpart_i);
  dim3 rg(BB / 256, 2);
  reduce_kernel<<<rg, 256, 0, stream>>>(rowpart_u, rowpart_i, rowsum_u, rowsum_i);
  finalize_kernel<<<1, 256, 0, stream>>>(rowsum_u, pos_u, rowsum_i, pos_i,
                                         sp_arr, rr_arr, (float*)d_out);
}

// Round 6
// 564.047 us; speedup vs baseline: 1.3655x; 1.1922x over previous
//
#include <hip/hip_runtime.h>
#include <hip/hip_bf16.h>
#include <math.h>

#define UCNT 50000
#define ICNT 25000
#define NNODE 75000
#define DDIM 64
#define BB 4096
#define EPS_C 0.2f
#define INV_TEMP 5.0f
#define NB_SCAN ((NNODE + 255) / 256)   // 293
#define NJT (BB / 64)                   // 64 j-tiles in infonce
#define NGRP 4                          // scatter groups (XCD pairs)

__device__ __forceinline__ float wave_sum(float x) {
#pragma unroll
  for (int m = 32; m >= 1; m >>= 1) x += __shfl_xor(x, m, 64);
  return x;
}

// ---------------- init ----------------
__global__ void init_kernel(int* __restrict__ counts) {
  int i = blockIdx.x * blockDim.x + threadIdx.x;
  if (i < NNODE) counts[i] = 0;
}

// ---------------- histogram + per-edge rank (coalesced rank write) ----------------
__global__ void hist_rank_kernel(const int* __restrict__ src, int* __restrict__ counts,
                                 int* __restrict__ rank, int ne) {
  int i = blockIdx.x * blockDim.x + threadIdx.x;
  int stride = gridDim.x * blockDim.x;
  for (; i < ne; i += stride) rank[i] = atomicAdd(&counts[src[i]], 1);
}

// ---------------- hierarchical scan: pass 1 — per-block sums ----------------
__global__ __launch_bounds__(256) void blocksum_kernel(const int* __restrict__ counts,
                                                       int* __restrict__ bsum, int n) {
  int t = threadIdx.x;
  int i = blockIdx.x * 256 + t;
  int c = (i < n) ? counts[i] : 0;
#pragma unroll
  for (int m = 32; m >= 1; m >>= 1) c += __shfl_xor(c, m, 64);
  __shared__ int ws[4];
  if ((t & 63) == 0) ws[t >> 6] = c;
  __syncthreads();
  if (t == 0) bsum[blockIdx.x] = ws[0] + ws[1] + ws[2] + ws[3];
}

// ---------------- hierarchical scan: pass 2 — scan the 293 block sums ----------------
__global__ __launch_bounds__(512) void bscan_kernel(const int* __restrict__ bsum,
                                                    int* __restrict__ boff, int nb) {
  int t = threadIdx.x;
  int lane = t & 63, wid = t >> 6;
  int c = (t < nb) ? bsum[t] : 0;
  int v = c;
#pragma unroll
  for (int d = 1; d < 64; d <<= 1) {
    int u = __shfl_up(v, d, 64);
    if (lane >= d) v += u;
  }
  __shared__ int ws[8], wo[8];
  if (lane == 63) ws[wid] = v;
  __syncthreads();
  if (t == 0) {
    int run = 0;
    for (int k = 0; k < 8; ++k) { wo[k] = run; run += ws[k]; }
  }
  __syncthreads();
  if (t < nb) boff[t] = v - c + wo[wid];
}

// ---------------- hierarchical scan: pass 3 — local scan + offset ----------------
__global__ __launch_bounds__(256) void scanout_kernel(const int* __restrict__ counts,
                                                      const int* __restrict__ boff,
                                                      int* __restrict__ row_ptr, int n) {
  int t = threadIdx.x;
  int lane = t & 63, wid = t >> 6;
  int i = blockIdx.x * 256 + t;
  int c = (i < n) ? counts[i] : 0;
  int v = c;
#pragma unroll
  for (int d = 1; d < 64; d <<= 1) {
    int u = __shfl_up(v, d, 64);
    if (lane >= d) v += u;
  }
  __shared__ int ws[4], wo[4];
  if (lane == 63) ws[wid] = v;
  __syncthreads();
  if (t == 0) {
    int run = 0;
    for (int k = 0; k < 4; ++k) { wo[k] = run; run += ws[k]; }
  }
  __syncthreads();
  int excl = v - c + wo[wid] + boff[blockIdx.x];
  if (i < n) {
    row_ptr[i] = excl;
    if (i == n - 1) row_ptr[n] = excl + c;
  }
}

// ---------------- slot: slot[i] = row_ptr[src[i]] + rank[i] (all coalesced) ----------
__global__ void slot_kernel(const int* __restrict__ src, const int* __restrict__ rank,
                            const int* __restrict__ row_ptr, int* __restrict__ slot, int ne) {
  int i = blockIdx.x * blockDim.x + threadIdx.x;
  int stride = gridDim.x * blockDim.x;
  for (; i < ne; i += stride) slot[i] = row_ptr[src[i]] + rank[i];
}

// ---------------- grouped scatter: each XCD pair sweeps all edges, writes its region --
// Correct for ANY block->XCD mapping (each slot written exactly once); the %8
// round-robin heuristic just makes each 2 MB csr region L2-resident on one XCD pair.
__global__ __launch_bounds__(256) void scatter_grouped_kernel(
    const int* __restrict__ slot, const int* __restrict__ dst,
    int* __restrict__ csr_dst, int ne) {
  int g = (blockIdx.x & 7) >> 1;               // group = XCD pair
  int bg = (blockIdx.x >> 3) * 2 + (blockIdx.x & 1);  // block index within group
  int nbg = (gridDim.x >> 3) * 2;
  int rsz = (ne + NGRP - 1) / NGRP;
  int lo = g * rsz;
  int hi = min(lo + rsz, ne);
  for (int i = bg * 256 + threadIdx.x; i < ne; i += nbg * 256) {
    int s = slot[i];
    if (s >= lo && s < hi) csr_dst[s] = dst[i];
  }
}

// ---------------- prescale: y_init[n] = table[n] * rsqrt(max(deg,1)) ----------------
__global__ __launch_bounds__(256) void prescale_kernel(const float* __restrict__ ut,
                                                       const float* __restrict__ it,
                                                       const int* __restrict__ counts,
                                                       float* __restrict__ y) {
  int idx = blockIdx.x * 256 + threadIdx.x;   // one float4 per thread
  if (idx >= NNODE * 16) return;
  int n = idx >> 4;
  float sc = rsqrtf(fmaxf((float)counts[n], 1.f));
  const float* srcp = (n < UCNT) ? (ut + (size_t)n * DDIM)
                                 : (it + (size_t)(n - UCNT) * DDIM);
  float4 v = *(const float4*)(srcp + (idx & 15) * 4);
  v.x *= sc; v.y *= sc; v.z *= sc; v.w *= sc;
  *(float4*)((float*)y + (size_t)idx * 4) = v;
}

// ---------------- SpMM (gather-sum of prescaled rows) + noise ----------------
__global__ __launch_bounds__(256) void spmm_kernel(const float* __restrict__ y_in,
                                                   const int* __restrict__ row_ptr,
                                                   const int* __restrict__ csr_dst,
                                                   const int* __restrict__ counts,
                                                   const float* __restrict__ noise,
                                                   float* __restrict__ y_out) {
  int wave = blockIdx.x * 4 + (threadIdx.x >> 6);
  int lane = threadIdx.x & 63;
  if (wave >= NNODE) return;
  int r = wave;
  int beg = row_ptr[r], endp = row_ptr[r + 1];
  int g = lane >> 4, l16 = lane & 15;
  float4 acc = {0.f, 0.f, 0.f, 0.f};
  for (int e0 = beg; e0 < endp; e0 += 64) {
    int e = e0 + lane;
    int d = (e < endp) ? csr_dst[e] : 0;
    int cnt = min(64, endp - e0);
    for (int j = 0; j < cnt; j += 4) {
      int dj = __shfl(d, j + g, 64);
      if (j + g < cnt) {    // group-uniform branch
        float4 xv = *(const float4*)(y_in + (size_t)dj * DDIM + l16 * 4);
        acc.x += xv.x; acc.y += xv.y; acc.z += xv.z; acc.w += xv.w;
      }
    }
  }
#pragma unroll
  for (int m = 16; m <= 32; m <<= 1) {
    acc.x += __shfl_xor(acc.x, m, 64);
    acc.y += __shfl_xor(acc.y, m, 64);
    acc.z += __shfl_xor(acc.z, m, 64);
    acc.w += __shfl_xor(acc.w, m, 64);
  }
  float sc = rsqrtf(fmaxf((float)counts[r], 1.f));
  acc.x *= sc; acc.y *= sc; acc.z *= sc; acc.w *= sc;   // x (pre-noise)
  float4 nf = *(const float4*)(noise + (size_t)r * DDIM + l16 * 4);
  float ss = nf.x * nf.x + nf.y * nf.y + nf.z * nf.z + nf.w * nf.w;
#pragma unroll
  for (int m = 1; m <= 8; m <<= 1) ss += __shfl_xor(ss, m, 64);  // 16-lane group = row
  float inv = EPS_C / fmaxf(sqrtf(ss), 1e-12f);
  float4 o;
  o.x = acc.x + ((acc.x > 0.f) ? 1.f : ((acc.x < 0.f) ? -1.f : 0.f)) * nf.x * inv;
  o.y = acc.y + ((acc.y > 0.f) ? 1.f : ((acc.y < 0.f) ? -1.f : 0.f)) * nf.y * inv;
  o.z = acc.z + ((acc.z > 0.f) ? 1.f : ((acc.z < 0.f) ? -1.f : 0.f)) * nf.z * inv;
  o.w = acc.w + ((acc.w > 0.f) ? 1.f : ((acc.w < 0.f) ? -1.f : 0.f)) * nf.w * inv;
  o.x *= sc; o.y *= sc; o.z *= sc; o.w *= sc;           // store y = x * sc
  if (g == 0) *(float4*)(y_out + (size_t)r * DDIM + l16 * 4) = o;
}

// ---------------- batch gather: BPR, reg, normalized InfoNCE inputs ----------------
__global__ __launch_bounds__(256) void batch_kernel(
    const float* __restrict__ yb0, const float* __restrict__ yb1, const float* __restrict__ yb2,
    const float* __restrict__ ut, const float* __restrict__ it,
    const int* __restrict__ counts,
    const int* __restrict__ user, const int* __restrict__ pos, const int* __restrict__ neg,
    float* __restrict__ z1u, float* __restrict__ z2u,
    float* __restrict__ z1i, float* __restrict__ z2i,
    float* __restrict__ pos_u, float* __restrict__ pos_i,
    float* __restrict__ sp_arr, float* __restrict__ rr_arr) {
  int wave = blockIdx.x * (blockDim.x >> 6) + (threadIdx.x >> 6);
  int lane = threadIdx.x & 63;
  if (wave >= BB) return;
  int b = wave;
  int iu = user[b], ip = pos[b], ing = neg[b];
  float s_u = sqrtf(fmaxf((float)counts[iu], 1.f));
  float s_p = sqrtf(fmaxf((float)counts[UCNT + ip], 1.f));
  float s_n = sqrtf(fmaxf((float)counts[UCNT + ing], 1.f));
  size_t ru = (size_t)iu * DDIM + lane;
  size_t rp = (size_t)(UCNT + ip) * DDIM + lane;
  size_t rn = (size_t)(UCNT + ing) * DDIM + lane;
  float cu = yb0[ru] * s_u;        // x_cl user row
  float ci = yb0[rp] * s_p;        // x_cl positive-item row
  float ue = (cu + (yb1[ru] + yb2[ru]) * s_u) * (1.f / 3.f);
  float pe = (ci + (yb1[rp] + yb2[rp]) * s_p) * (1.f / 3.f);
  float ne = (yb0[rn] + yb1[rn] + yb2[rn]) * s_n * (1.f / 3.f);

  float ps = wave_sum(ue * pe);
  float ns = wave_sum(ue * ne);
  float x = ns - ps;
  float sp = fmaxf(x, 0.f) + log1pf(expf(-fabsf(x)));

  float eu = ut[(size_t)iu * DDIM + lane];
  float ep = it[(size_t)ip * DDIM + lane];
  float en = it[(size_t)ing * DDIM + lane];
  float rr = wave_sum(eu * eu + ep * ep + en * en);
  if (lane == 0) { sp_arr[b] = sp; rr_arr[b] = rr; }

  float n1 = fmaxf(sqrtf(wave_sum(cu * cu)), 1e-12f);
  float n2 = fmaxf(sqrtf(wave_sum(ue * ue)), 1e-12f);
  float d12 = wave_sum(cu * ue);
  z1u[(size_t)b * DDIM + lane] = cu / n1;
  z2u[(size_t)b * DDIM + lane] = ue / n2;
  if (lane == 0) pos_u[b] = d12 / (n1 * n2) * INV_TEMP;

  float m1 = fmaxf(sqrtf(wave_sum(ci * ci)), 1e-12f);
  float m2 = fmaxf(sqrtf(wave_sum(pe * pe)), 1e-12f);
  float e12 = wave_sum(ci * pe);
  z1i[(size_t)b * DDIM + lane] = ci / m1;
  z2i[(size_t)b * DDIM + lane] = pe / m2;
  if (lane == 0) pos_i[b] = e12 / (m1 * m2) * INV_TEMP;
}

// ---------------- InfoNCE similarity tile: partial per (jtile,row), NO atomics --------
__global__ __launch_bounds__(256) void infonce_kernel(const float* __restrict__ Z1,
                                                      const float* __restrict__ Z2,
                                                      float* __restrict__ rowpart) {
  __shared__ float S1[64][65];
  __shared__ float S2[64][65];
  __shared__ float red[64][17];
  int t = threadIdx.x;
  int i0 = blockIdx.y * 64, j0 = blockIdx.x * 64;
#pragma unroll
  for (int rep = 0; rep < 4; ++rep) {
    int vlin = rep * 256 + t;       // float4 index in 64x16
    int row = vlin >> 4;
    int c4 = (vlin & 15) * 4;
    float4 a = *(const float4*)(Z1 + (size_t)(i0 + row) * DDIM + c4);
    S1[c4 + 0][row] = a.x; S1[c4 + 1][row] = a.y; S1[c4 + 2][row] = a.z; S1[c4 + 3][row] = a.w;
    float4 b = *(const float4*)(Z2 + (size_t)(j0 + row) * DDIM + c4);
    S2[c4 + 0][row] = b.x; S2[c4 + 1][row] = b.y; S2[c4 + 2][row] = b.z; S2[c4 + 3][row] = b.w;
  }
  __syncthreads();
  int ti = (t & 15) * 4;
  int tj = (t >> 4) * 4;
  float acc[4][4] = {};
  for (int k = 0; k < 64; ++k) {
    float4 av = *(const float4*)&S1[k][ti];
    float4 bv = *(const float4*)&S2[k][tj];
    float a[4] = {av.x, av.y, av.z, av.w};
    float b[4] = {bv.x, bv.y, bv.z, bv.w};
#pragma unroll
    for (int r = 0; r < 4; ++r)
#pragma unroll
      for (int c = 0; c < 4; ++c) acc[r][c] += a[r] * b[c];
  }
  int q = t >> 4;
#pragma unroll
  for (int r = 0; r < 4; ++r) {
    float s = __expf(acc[r][0] * INV_TEMP) + __expf(acc[r][1] * INV_TEMP) +
              __expf(acc[r][2] * INV_TEMP) + __expf(acc[r][3] * INV_TEMP);
    red[ti + r][q] = s;
  }
  __syncthreads();
  if (t < 64) {
    float tot = 0.f;
#pragma unroll
    for (int q2 = 0; q2 < 16; ++q2) tot += red[t][q2];
    rowpart[(size_t)blockIdx.x * BB + i0 + t] = tot;   // coalesced, no atomic
  }
}

// ---------------- reduce 64 partials per row into rowsum ----------------
__global__ __launch_bounds__(256) void reduce_kernel(const float* __restrict__ rowpart_u,
                                                     const float* __restrict__ rowpart_i,
                                                     float* __restrict__ rowsum_u,
                                                     float* __restrict__ rowsum_i) {
  int i = blockIdx.x * 256 + threadIdx.x;   // row index
  const float* src = blockIdx.y ? rowpart_i : rowpart_u;
  float s = 0.f;
#pragma unroll 8
  for (int jb = 0; jb < NJT; ++jb) s += src[(size_t)jb * BB + i];
  if (blockIdx.y) rowsum_i[i] = s; else rowsum_u[i] = s;
}

// ---------------- finalize ----------------
__global__ __launch_bounds__(256) void finalize_kernel(const float* __restrict__ rowsum_u,
                                                       const float* __restrict__ pos_u,
                                                       const float* __restrict__ rowsum_i,
                                                       const float* __restrict__ pos_i,
                                                       const float* __restrict__ sp_arr,
                                                       const float* __restrict__ rr_arr,
                                                       float* __restrict__ out) {
  int t = threadIdx.x;
  float su = 0.f, si = 0.f, sb = 0.f, sr = 0.f;
  for (int i = t; i < BB; i += 256) {
    su += logf(rowsum_u[i]) - pos_u[i];
    si += logf(rowsum_i[i]) - pos_i[i];
    sb += sp_arr[i];
    sr += rr_arr[i];
  }
  su = wave_sum(su);
  si = wave_sum(si);
  sb = wave_sum(sb);
  sr = wave_sum(sr);
  __shared__ float sh[16];
  int lane = t & 63, wid = t >> 6;
  if (lane == 0) { sh[wid] = su; sh[4 + wid] = si; sh[8 + wid] = sb; sh[12 + wid] = sr; }
  __syncthreads();
  if (t == 0) {
    float SU = sh[0] + sh[1] + sh[2] + sh[3];
    float SI = sh[4] + sh[5] + sh[6] + sh[7];
    float SB = sh[8] + sh[9] + sh[10] + sh[11];
    float SR = sh[12] + sh[13] + sh[14] + sh[15];
    out[0] = SB * (1.f / BB);
    out[1] = 1e-4f * 0.5f * SR * (1.f / BB);
    out[2] = 0.2f * ((SU + SI) * (1.f / BB));
  }
}

extern "C" void kernel_launch(void* const* d_in, const int* in_sizes, int n_in,
                              void* d_out, int out_size, void* d_ws, size_t ws_size,
                              hipStream_t stream) {
  const float* user_table = (const float*)d_in[0];
  const float* item_table = (const float*)d_in[1];
  const float* noise      = (const float*)d_in[3];
  const int*   edge_src   = (const int*)d_in[4];
  const int*   edge_dst   = (const int*)d_in[5];
  const int*   user       = (const int*)d_in[6];
  const int*   positive   = (const int*)d_in[7];
  const int*   negative   = (const int*)d_in[8];
  const int E2 = in_sizes[2];  // 2,000,000

  char* w = (char*)d_ws;
  auto alloc = [&](size_t bytes) -> void* {
    void* p = (void*)w;
    w += (bytes + 255) & ~(size_t)255;
    return p;
  };
  int*   counts   = (int*)alloc((size_t)NNODE * 4);
  int*   row_ptr  = (int*)alloc((size_t)(NNODE + 1) * 4);
  int*   rank     = (int*)alloc((size_t)E2 * 4);
  int*   slot     = (int*)alloc((size_t)E2 * 4);
  int*   bsum     = (int*)alloc((size_t)NB_SCAN * 4);
  int*   boff     = (int*)alloc((size_t)NB_SCAN * 4);
  int*   csr_dst  = (int*)alloc((size_t)E2 * 4);
  float* y_init   = (float*)alloc((size_t)NNODE * DDIM * 4);
  float* yb0      = (float*)alloc((size_t)NNODE * DDIM * 4);
  float* yb1      = (float*)alloc((size_t)NNODE * DDIM * 4);
  float* yb2      = (float*)alloc((size_t)NNODE * DDIM * 4);
  float* z1u      = (float*)alloc((size_t)BB * DDIM * 4);
  float* z2u      = (float*)alloc((size_t)BB * DDIM * 4);
  float* z1i      = (float*)alloc((size_t)BB * DDIM * 4);
  float* z2i      = (float*)alloc((size_t)BB * DDIM * 4);
  float* pos_u    = (float*)alloc((size_t)BB * 4);
  float* pos_i    = (float*)alloc((size_t)BB * 4);
  float* rowsum_u = (float*)alloc((size_t)BB * 4);
  float* rowsum_i = (float*)alloc((size_t)BB * 4);
  float* sp_arr   = (float*)alloc((size_t)BB * 4);
  float* rr_arr   = (float*)alloc((size_t)BB * 4);
  float* rowpart_u = (float*)alloc((size_t)NJT * BB * 4);
  float* rowpart_i = (float*)alloc((size_t)NJT * BB * 4);

  init_kernel<<<(NNODE + 255) / 256, 256, 0, stream>>>(counts);
  hist_rank_kernel<<<2048, 256, 0, stream>>>(edge_src, counts, rank, E2);
  blocksum_kernel<<<NB_SCAN, 256, 0, stream>>>(counts, bsum, NNODE);
  bscan_kernel<<<1, 512, 0, stream>>>(bsum, boff, NB_SCAN);
  scanout_kernel<<<NB_SCAN, 256, 0, stream>>>(counts, boff, row_ptr, NNODE);
  slot_kernel<<<2048, 256, 0, stream>>>(edge_src, rank, row_ptr, slot, E2);
  scatter_grouped_kernel<<<2048, 256, 0, stream>>>(slot, edge_dst, csr_dst, E2);
  prescale_kernel<<<(NNODE * 16 + 255) / 256, 256, 0, stream>>>(user_table, item_table,
                                                                counts, y_init);
  const int spmm_blocks = (NNODE + 3) / 4;  // 4 waves per 256-thread block
  spmm_kernel<<<spmm_blocks, 256, 0, stream>>>(y_init, row_ptr, csr_dst, counts,
                                               noise + (size_t)0 * NNODE * DDIM, yb0);
  spmm_kernel<<<spmm_blocks, 256, 0, stream>>>(yb0, row_ptr, csr_dst, counts,
                                               noise + (size_t)1 * NNODE * DDIM, yb1);
  spmm_kernel<<<spmm_blocks, 256, 0, stream>>>(yb1, row_ptr, csr_dst, counts,
                                               noise + (size_t)2 * NNODE * DDIM, yb2);
  batch_kernel<<<BB / 4, 256, 0, stream>>>(yb0, yb1, yb2, user_table, item_table, counts,
                                           user, positive, negative,
                                           z1u, z2u, z1i, z2i, pos_u, pos_i, sp_arr, rr_arr);
  dim3 ig(NJT, NJT);
  infonce_kernel<<<ig, 256, 0, stream>>>(z1u, z2u, rowpart_u);
  infonce_kernel<<<ig, 256, 0, stream>>>(z1i, z2i, rowpart_i);
  dim3 rg(BB / 256, 2);
  reduce_kernel<<<rg, 256, 0, stream>>>(rowpart_u, rowpart_i, rowsum_u, rowsum_i);
  finalize_kernel<<<1, 256, 0, stream>>>(rowsum_u, pos_u, rowsum_i, pos_i,
                                         sp_arr, rr_arr, (float*)d_out);
}